// Round 7
// baseline (22885.751 us; speedup 1.0000x reference)
//
#include <hip/hip_runtime.h>

typedef unsigned short ushort_t;
typedef unsigned int uint_t;
typedef float f32x4_t __attribute__((ext_vector_type(4)));
typedef short bf16x8_t __attribute__((ext_vector_type(8)));

// ---- problem constants ----
#define NBATCH 16
#define SMEM   256
#define TSTEPS 400

// ---- workspace layout (float offsets) ----
#define F_XSB   0u         // 400*16*256 bf16 = 819200 floats
#define F_PM    819200u    // 16*256*128 f32
#define F_MMIX  1343488u   // 16*81*256 f32 (M_b = Wctx . mem^T)
#define F_W1T   1675264u
#define F_W2T   1695744u
// ---- zeroed region ----
#define F_AHB   1761280u   // 2*16*1024 bf16 = 16384 floats
#define F_DHB   1777664u   // 16384
#define F_CTXB  1794048u   // 2*16*512 bf16 = 8192 floats
#define F_DHF   1802240u   // 2*16*1024 f32 = 32768
#define F_AWG   1835008u   // 2*16*256 f32 = 8192
#define F_FLG   1843200u   // 344 slots * 16 ints = 5504
#define ZERO_BASE  F_AHB
#define ZERO_COUNT 87424u

// flag slot bases
#define AHF  0
#define CTXF 64
#define DHFL 192
#define AWF  320
#define PRF  336

struct Ptrs {
  const float *memory, *dec_in, *Wpre1, *Wpre2, *Wih_a, *Whh_a, *bih_a, *bhh_a,
              *Wq, *Wm, *v, *Wc, *Wld, *Wih_d, *Whh_d, *bih_d, *bhh_d,
              *Wproj, *bproj, *Wgate, *bgate;
  const int *mlen;
  float *ws;
  float *out;
};

__device__ __forceinline__ float ftanh(float x) {
  float e = __expf(2.f * x);
  return 1.f - 2.f / (e + 1.f);
}
__device__ __forceinline__ float fsig(float x) { return 1.f / (1.f + __expf(-x)); }

__device__ __forceinline__ unsigned f2bfbits(float x) {
  unsigned u = __builtin_bit_cast(unsigned, x);
  return (u + 0x7FFFu + ((u >> 16) & 1u)) >> 16;
}
__device__ __forceinline__ float bf2f(ushort_t u) {
  unsigned v = ((unsigned)u) << 16;
  return __builtin_bit_cast(float, v);
}
__device__ __forceinline__ bf16x8_t packbf8(const float* f) {
  bf16x8_t r;
#pragma unroll
  for (int j = 0; j < 8; ++j) r[j] = (short)f2bfbits(f[j]);
  return r;
}
__device__ __forceinline__ bf16x8_t pack_from_f4(const float* src) {
  const float4* s4 = (const float4*)src;
  float4 lo = s4[0], hi = s4[1];
  float tmp[8] = {lo.x, lo.y, lo.z, lo.w, hi.x, hi.y, hi.z, hi.w};
  return packbf8(tmp);
}
__device__ __forceinline__ bf16x8_t ldbf8(const ushort_t* p) {
  return *(const bf16x8_t*)p;
}
struct ull2 { unsigned long long x, y; };
__device__ __forceinline__ bf16x8_t ldbf8_a(const ushort_t* p) {
  ull2 v;
  v.x = __hip_atomic_load((const unsigned long long*)p, __ATOMIC_RELAXED, __HIP_MEMORY_SCOPE_AGENT);
  v.y = __hip_atomic_load(((const unsigned long long*)p) + 1, __ATOMIC_RELAXED, __HIP_MEMORY_SCOPE_AGENT);
  return __builtin_bit_cast(bf16x8_t, v);
}
__device__ __forceinline__ void stull_a(unsigned long long* p, unsigned long long v) {
  __hip_atomic_store(p, v, __ATOMIC_RELAXED, __HIP_MEMORY_SCOPE_AGENT);
}
__device__ __forceinline__ void stf_a(float* p, float v) {
  __hip_atomic_store(p, v, __ATOMIC_RELAXED, __HIP_MEMORY_SCOPE_AGENT);
}
__device__ __forceinline__ float ldf_a(const float* p) {
  return __hip_atomic_load(p, __ATOMIC_RELAXED, __HIP_MEMORY_SCOPE_AGENT);
}
// busy-spin poll: no s_sleep (wave sleep/wake quantum was the suspected hop cost)
__device__ __forceinline__ void pollge(int* flg, int slot, int thr) {
  while (__hip_atomic_load(flg + slot * 16, __ATOMIC_RELAXED, __HIP_MEMORY_SCOPE_AGENT) < thr) {}
}
__device__ __forceinline__ void sig(int* flg, int slot, int val) {
  __hip_atomic_store(flg + slot * 16, val, __ATOMIC_RELAXED, __HIP_MEMORY_SCOPE_AGENT);
}
#define MFMA16(a,b,c) __builtin_amdgcn_mfma_f32_16x16x32_bf16((a),(b),(c),0,0,0)

// ---------------- zero state ----------------
__global__ __launch_bounds__(256) void k_zero(Ptrs p) {
  unsigned i = blockIdx.x * 256 + threadIdx.x;
  if (i < ZERO_COUNT) p.ws[ZERO_BASE + i] = 0.f;
}

// ---------------- weight transposes for prenet ----------------
__global__ __launch_bounds__(256) void k_transpose(Ptrs p) {
  int i = blockIdx.x * 256 + threadIdx.x;
  if (i < 20480) {
    int m = i >> 8, c = i & 255;
    p.ws[F_W1T + i] = p.Wpre1[c * 80 + m];
  } else if (i < 20480 + 65536) {
    int j = i - 20480;
    int pp = j >> 8, q = j & 255;
    p.ws[F_W2T + j] = p.Wpre2[q * 256 + pp];
  }
}

// ---------------- prenet -> xsb (bf16) ----------------
__global__ __launch_bounds__(256) void k_prenet(Ptrs p) {
  __shared__ float dil[NBATCH * 80];
  __shared__ float h1[NBATCH * 256];
  const int t = blockIdx.x, tid = threadIdx.x;
  const float* W1T = p.ws + F_W1T;
  const float* W2T = p.ws + F_W2T;

  for (int i = tid; i < NBATCH * 80; i += 256) {
    int b = i / 80, m = i - b * 80;
    dil[i] = (t == 0) ? 0.f : p.dec_in[((size_t)b * 80 + m) * 400 + (t - 1)];
  }
  __syncthreads();

  float acc[NBATCH];
#pragma unroll
  for (int b = 0; b < NBATCH; ++b) acc[b] = 0.f;
  for (int m = 0; m < 80; ++m) {
    float w = W1T[m * 256 + tid];
#pragma unroll
    for (int b = 0; b < NBATCH; ++b) acc[b] = fmaf(dil[b * 80 + m], w, acc[b]);
  }
#pragma unroll
  for (int b = 0; b < NBATCH; ++b) h1[b * 256 + tid] = fmaxf(acc[b], 0.f);
  __syncthreads();

#pragma unroll
  for (int b = 0; b < NBATCH; ++b) acc[b] = 0.f;
  for (int q = 0; q < 256; ++q) {
    float w = W2T[q * 256 + tid];
#pragma unroll
    for (int b = 0; b < NBATCH; ++b) acc[b] = fmaf(h1[b * 256 + q], w, acc[b]);
  }
  ushort_t* xsbU = (ushort_t*)(p.ws + F_XSB);
#pragma unroll
  for (int b = 0; b < NBATCH; ++b)
    xsbU[((size_t)(t * NBATCH + b)) * 256 + tid] = (ushort_t)f2bfbits(fmaxf(acc[b], 0.f));
}

// ---------------- proc_mem fp32 ----------------
__global__ __launch_bounds__(256) void k_procmem(Ptrs p) {
  __shared__ alignas(16) float msl[16 * 512];
  const int b = blockIdx.x >> 4, s0 = (blockIdx.x & 15) << 4;
  const int tid = threadIdx.x;
  const float4* src = (const float4*)(p.memory + ((size_t)(b * SMEM + s0)) * 512);
  float4* dst = (float4*)msl;
  for (int i = tid; i < 16 * 512 / 4; i += 256) dst[i] = src[i];
  __syncthreads();

  const int a = tid & 127, sg = tid >> 7;
  const float4* wm = (const float4*)(p.Wm + (size_t)a * 512);
  float* pm = p.ws + F_PM;
  float acc[8];
#pragma unroll
  for (int j = 0; j < 8; ++j) acc[j] = 0.f;
  for (int k = 0; k < 128; ++k) {
    float4 w = wm[k];
#pragma unroll
    for (int j = 0; j < 8; ++j) {
      float4 m = ((const float4*)(msl + (size_t)(sg * 8 + j) * 512))[k];
      acc[j] += w.x * m.x + w.y * m.y + w.z * m.z + w.w * m.w;
    }
  }
#pragma unroll
  for (int j = 0; j < 8; ++j)
    pm[((size_t)(b * SMEM + s0 + sg * 8 + j)) * 128 + a] = acc[j];
}

// ---------------- premix: M[b][row][s] = Wctx[row][:] . memory[b][s][:] ----------------
__global__ __launch_bounds__(512) void k_premix(Ptrs p) {
  const int b = blockIdx.x, tid = threadIdx.x;
  float* M = p.ws + F_MMIX;
  for (int i = tid; i < 81 * 256; i += 512) {
    int row = i >> 8, s = i & 255;
    const float* wrow = (row < 80) ? p.Wproj + (size_t)row * 1536 + 1024 : p.Wgate + 1024;
    const float4* w4 = (const float4*)wrow;
    const float4* m4 = (const float4*)(p.memory + ((size_t)(b * 256 + s)) * 512);
    float acc = 0.f;
#pragma unroll 4
    for (int k = 0; k < 128; ++k) {
      float4 w = w4[k], m = m4[k];
      acc += w.x * m.x + w.y * m.y + w.z * m.z + w.w * m.w;
    }
    M[((size_t)b * 81 + row) * 256 + s] = acc;
  }
}

// ---------------- persistent dataflow scan: 256 blocks x 512 threads ----------------
__global__ __launch_bounds__(512, 1) void k_scan(Ptrs p) {
  __shared__ alignas(16) float sm[12288];   // 48 KB
  const int bid = blockIdx.x, tid = threadIdx.x;
  const int wid = tid >> 6, lane = tid & 63;
  const int m16 = lane & 15, kq = lane >> 4;

  float* ws = p.ws;
  ushort_t* xsbU  = (ushort_t*)(ws + F_XSB);
  float*    pmF   = ws + F_PM;
  float*    Mx    = ws + F_MMIX;
  ushort_t* ahbU  = (ushort_t*)(ws + F_AHB);
  unsigned long long* ahb8 = (unsigned long long*)(ws + F_AHB);
  ushort_t* dhbU  = (ushort_t*)(ws + F_DHB);
  unsigned long long* dhb8 = (unsigned long long*)(ws + F_DHB);
  ushort_t* ctxbU = (ushort_t*)(ws + F_CTXB);
  unsigned long long* ctxb8 = (unsigned long long*)(ws + F_CTXB);
  float*    dhfF  = ws + F_DHF;
  float*    awGF  = ws + F_AWG;
  int*      flg   = (int*)(ws + F_FLG);
  float* out_mel  = p.out;
  float* out_gate = p.out + 512000;
  float* out_al   = p.out + 518400;

  if (bid < 64) {
    // ======== A-path: A-LSTM(t); 8 waves = 4 strips x 2 K-halves ========
    const int ls = wid >> 1, half = wid & 1;
    const int strip = (bid << 2) | ls;
    const int gA = m16 & 3, jA = m16 >> 2;
    const int wrowA = gA * 1024 + strip * 4 + jA;
    bf16x8_t wA[28];
#pragma unroll
    for (int c = 0; c < 28; ++c) {
      int k0 = (half * 28 + c) * 32 + kq * 8;
      const float* src = (k0 < 768) ? p.Wih_a + (size_t)wrowA * 768 + k0
                                    : p.Whh_a + (size_t)wrowA * 1024 + (k0 - 768);
      wA[c] = pack_from_f4(src);
    }
    const int nnA = strip * 4 + kq;
    float biasA[4];
#pragma unroll
    for (int r = 0; r < 4; ++r) biasA[r] = p.bih_a[r * 1024 + nnA] + p.bhh_a[r * 1024 + nnA];
    float acState = 0.f;
    __syncthreads();

    for (int t = 0; t < TSTEPS; ++t) {
      const int pc = t & 1, pp = (t + 1) & 1;
      // waits: ah(t-1) [AHF>=t], ctx(t-1) [CTXF>=t], WAR on ah slot [DHFL>=t-1]
      if (tid < 64) pollge(flg, AHF + tid, t);
      else if (tid < 192) pollge(flg, CTXF + tid - 64, t);
      else if (tid < 320) pollge(flg, DHFL + tid - 192, t - 1);
      __syncthreads();

      f32x4_t a0 = {0,0,0,0}, a1 = {0,0,0,0};
      const ushort_t* xsrc = xsbU + ((size_t)t * 16 + m16) * 256;
      const ushort_t* csrc = ctxbU + (size_t)pp * 8192 + m16 * 512;
      const ushort_t* hsrc = ahbU + (size_t)pp * 16384 + m16 * 1024;
      if (half == 0) {
#pragma unroll
        for (int c = 0; c < 28; ++c) {
          bf16x8_t bf;
          if (c < 8)       bf = ldbf8(xsrc + c * 32 + kq * 8);
          else if (c < 24) bf = ldbf8_a(csrc + (c - 8) * 32 + kq * 8);
          else             bf = ldbf8_a(hsrc + (c - 24) * 32 + kq * 8);
          if (c & 1) a1 = MFMA16(wA[c], bf, a1); else a0 = MFMA16(wA[c], bf, a0);
        }
      } else {
#pragma unroll
        for (int c = 0; c < 28; ++c) {
          bf16x8_t bf = ldbf8_a(hsrc + (4 + c) * 32 + kq * 8);
          if (c & 1) a1 = MFMA16(wA[c], bf, a1); else a0 = MFMA16(wA[c], bf, a0);
        }
#pragma unroll
        for (int r = 0; r < 4; ++r) sm[((ls * 64 + lane) << 2) + r] = a0[r] + a1[r];
      }
      __syncthreads();
      if (half == 0) {
        float z[4];
#pragma unroll
        for (int r = 0; r < 4; ++r)
          z[r] = a0[r] + a1[r] + sm[((ls * 64 + lane) << 2) + r] + biasA[r];
        float cn = fsig(z[1]) * acState + fsig(z[0]) * ftanh(z[2]);
        acState = cn;
        float h = fsig(z[3]) * ftanh(cn);
        unsigned hb = f2bfbits(h);
        unsigned b0 = __shfl(hb, m16);
        unsigned b1 = __shfl(hb, m16 + 16);
        unsigned b2 = __shfl(hb, m16 + 32);
        unsigned b3 = __shfl(hb, m16 + 48);
        if (kq == 0) {
          unsigned long long u = (unsigned long long)(b0 | (b1 << 16))
                               | ((unsigned long long)(b2 | (b3 << 16)) << 32);
          stull_a(ahb8 + ((size_t)(pc * 16 + m16)) * 256 + strip, u);
        }
      }
      __syncthreads();   // drains vmcnt(0) before flag (compiler-inserted before s_barrier)
      if (tid == 0) sig(flg, AHF + bid, t + 1);
    }
  } else if (bid < 192) {
    // ======== D-path: ctx(t) FIRST (critical), then D-LSTM(t-1) (off-path) ========
    const int ls = wid >> 2, qt = wid & 3;
    const int strip = ((bid - 64) << 1) | ls;
    const int gD = m16 & 3, jD = m16 >> 2;
    const int wrowD = gD * 1024 + strip * 4 + jD;
    bf16x8_t wD[20];
#pragma unroll
    for (int c = 0; c < 20; ++c) {
      int k0 = (qt * 20 + c) * 32 + kq * 8;
      const float* src = (k0 < 1536) ? p.Wih_d + (size_t)wrowD * 1536 + k0
                                     : p.Whh_d + (size_t)wrowD * 1024 + (k0 - 1536);
      wD[c] = pack_from_f4(src);
    }
    const int nnD = strip * 4 + kq;
    float biasD[4];
#pragma unroll
    for (int r = 0; r < 4; ++r) biasD[r] = p.bih_d[r * 1024 + nnD] + p.bhh_d[r * 1024 + nnD];
    float dcState = 0.f;

    const int cb = (bid - 64) >> 3, sl = (bid - 64) & 7;
    float* comb = sm;               // 1536
    float* awsm = sm + 1536;        // 256
    float* part = sm + 1792;        // 512
    ushort_t* memu = (ushort_t*)(sm + 2304);   // 16384 ushorts
    for (int i = tid; i < 16384; i += 512) {
      int s = i >> 6, c = i & 63;
      memu[i] = (ushort_t)f2bfbits(p.memory[((size_t)cb * 256 + s) * 512 + sl * 64 + c]);
    }
    __syncthreads();

    for (int t = 0; t <= TSTEPS; ++t) {
      const int pc = t & 1, pw = (t + 1) & 1;
      // ---- phase 1: ctx(t) (critical path) ----
      if (t < TSTEPS) {
        // waits: aw(t) [AWF>=t+1]; WAR ctx slot [DHFL>=t-1]; WAR dhf [PRF>=t-2]
        if (tid == 0) pollge(flg, AWF + cb, t + 1);
        else if (tid >= 64 && tid < 192) pollge(flg, DHFL + tid - 64, t - 1);
        else if (tid >= 192 && tid < 200) pollge(flg, PRF + tid - 192, t - 2);
        __syncthreads();
        if (tid < 256) awsm[tid] = ldf_a(awGF + (size_t)pc * 4096 + cb * 256 + tid);
        __syncthreads();
        const int c = tid & 63, sg = tid >> 6;
        float acc = 0.f;
#pragma unroll 8
        for (int si = 0; si < 32; ++si) {
          int s = sg * 32 + si;
          acc = fmaf(awsm[s], bf2f(memu[s * 64 + c]), acc);
        }
        part[sg * 64 + c] = acc;
        __syncthreads();
        if (tid < 64) {
          float v = 0.f;
#pragma unroll
          for (int j = 0; j < 8; ++j) v += part[j * 64 + tid];
          unsigned vb = f2bfbits(v);
          int base = tid & ~3;
          unsigned c0 = __shfl(vb, base);
          unsigned c1 = __shfl(vb, base + 1);
          unsigned c2 = __shfl(vb, base + 2);
          unsigned c3 = __shfl(vb, base + 3);
          if ((tid & 3) == 0) {
            unsigned long long u = (unsigned long long)(c0 | (c1 << 16))
                                 | ((unsigned long long)(c2 | (c3 << 16)) << 32);
            stull_a(ctxb8 + ((size_t)(pc * 16 + cb)) * 128 + ((sl * 64 + tid) >> 2), u);
          }
        }
        __syncthreads();
        if (tid == 0) sig(flg, CTXF + (bid - 64), t + 1);
      }
      // ---- phase 2: D-LSTM(t-1) (overlaps next step's A/ATT) ----
      if (t >= 1) {
        if (tid < 128) pollge(flg, CTXF + tid, t);   // full ctx(t-1)
        __syncthreads();

        f32x4_t a0 = {0,0,0,0}, a1 = {0,0,0,0};
        const ushort_t* hsrc = ahbU + (size_t)pw * 16384 + m16 * 1024;
        const ushort_t* csrc = ctxbU + (size_t)pw * 8192 + m16 * 512;
        const ushort_t* dsrc = dhbU + (size_t)pc * 16384 + m16 * 1024;
#define DMFMA(SRC, OFF) { bf16x8_t bf = ldbf8_a((SRC) + (OFF) * 32 + kq * 8); \
          if (c & 1) a1 = MFMA16(wD[c], bf, a1); else a0 = MFMA16(wD[c], bf, a0); }
        if (qt == 0) {
#pragma unroll
          for (int c = 0; c < 20; ++c) DMFMA(hsrc, c)
        } else if (qt == 1) {
#pragma unroll
          for (int c = 0; c < 20; ++c) { if (c < 12) DMFMA(hsrc, 20 + c) else DMFMA(csrc, c - 12) }
        } else if (qt == 2) {
#pragma unroll
          for (int c = 0; c < 20; ++c) { if (c < 8) DMFMA(csrc, 8 + c) else DMFMA(dsrc, c - 8) }
        } else {
#pragma unroll
          for (int c = 0; c < 20; ++c) DMFMA(dsrc, 12 + c)
        }
#undef DMFMA
        if (qt != 0) {
#pragma unroll
          for (int r = 0; r < 4; ++r)
            comb[(((ls * 3 + qt - 1) * 64 + lane) << 2) + r] = a0[r] + a1[r];
        }
        __syncthreads();
        if (qt == 0) {
          float z[4];
#pragma unroll
          for (int r = 0; r < 4; ++r) {
            z[r] = a0[r] + a1[r] + biasD[r];
#pragma unroll
            for (int j = 0; j < 3; ++j) z[r] += comb[(((ls * 3 + j) * 64 + lane) << 2) + r];
          }
          float cn = fsig(z[1]) * dcState + fsig(z[0]) * ftanh(z[2]);
          dcState = cn;
          float h = fsig(z[3]) * ftanh(cn);
          stf_a(dhfF + (size_t)pw * 16384 + m16 * 1024 + nnD, h);
          unsigned hb = f2bfbits(h);
          unsigned b0 = __shfl(hb, m16);
          unsigned b1 = __shfl(hb, m16 + 16);
          unsigned b2 = __shfl(hb, m16 + 32);
          unsigned b3 = __shfl(hb, m16 + 48);
          if (kq == 0) {
            unsigned long long u = (unsigned long long)(b0 | (b1 << 16))
                                 | ((unsigned long long)(b2 | (b3 << 16)) << 32);
            stull_a(dhb8 + ((size_t)(pw * 16 + m16)) * 256 + strip, u);
          }
        }
        __syncthreads();
        if (tid == 0) sig(flg, DHFL + (bid - 64), t);
      }
    }
  } else if (bid < 208) {
    // ======== ATT path: one block per batch ========
    const int b = bid - 192;
    const int mlenb = p.mlen[b];
    ushort_t* locu = (ushort_t*)sm;        // 256*40 ushorts = 5120 floats
    float* qsm   = sm + 5120;
    float* vsm   = sm + 5248;
    float* esm   = sm + 5376;
    float* red   = sm + 5632;
    float* smaw  = sm + 5648;
    float* smawc = sm + 5904;

    bf16x8_t wq[32];
#pragma unroll
    for (int c = 0; c < 32; ++c)
      wq[c] = pack_from_f4(p.Wq + (size_t)(wid * 16 + m16) * 1024 + c * 32 + kq * 8);
    bf16x8_t wLd[8];
#pragma unroll
    for (int at = 0; at < 8; ++at)
      wLd[at] = pack_from_f4(p.Wld + ((size_t)(at * 16 + m16)) * 32 + kq * 8);
    bf16x8_t wC[2][2];
#pragma unroll
    for (int ft = 0; ft < 2; ++ft)
#pragma unroll
      for (int ck = 0; ck < 2; ++ck) {
        float tmp[8];
#pragma unroll
        for (int jj = 0; jj < 8; ++jj) {
          int k2 = ck * 32 + kq * 8 + jj;
          float vv = 0.f;
          if (k2 < 62) { int ch = (k2 < 31) ? 0 : 1; int k = k2 - 31 * ch;
            vv = p.Wc[((size_t)(ft * 16 + m16) * 2 + ch) * 31 + k]; }
          tmp[jj] = vv;
        }
        wC[ft][ck] = packbf8(tmp);
      }
    // pm -> registers
    uint_t pmreg[2][8][2];
#pragma unroll
    for (int u = 0; u < 2; ++u) {
      int sloc = (wid * 2 + u) * 16 + m16;
#pragma unroll
      for (int at = 0; at < 8; ++at)
#pragma unroll
        for (int rp = 0; rp < 2; ++rp) {
          const float* src = pmF + ((size_t)(b * 256 + sloc)) * 128 + at * 16 + kq * 4 + rp * 2;
          pmreg[u][at][rp] = f2bfbits(src[0]) | (f2bfbits(src[1]) << 16);
        }
    }
    if (tid < 128) vsm[tid] = p.v[tid];
    if (tid < 256) { smaw[tid] = 0.f; smawc[tid] = 0.f; }
    __syncthreads();

    for (int t = 0; t < TSTEPS; ++t) {
      const int pc = t & 1;
      // conv(t) from LDS aw/awc — before any wait (off critical path)
#pragma unroll
      for (int u = 0; u < 4; ++u) {
        int task = wid * 4 + u;
        int stile = task >> 1, ft = task & 1;
        int scol = stile * 16 + m16;
        f32x4_t acc = {0,0,0,0};
#pragma unroll
        for (int ck = 0; ck < 2; ++ck) {
          float tmp[8];
#pragma unroll
          for (int jj = 0; jj < 8; ++jj) {
            int k2 = ck * 32 + kq * 8 + jj;
            float vv = 0.f;
            if (k2 < 62) {
              int ch = (k2 < 31) ? 0 : 1; int k = k2 - 31 * ch;
              int sp = scol + k - 15;
              if (sp >= 0 && sp < 256) vv = (ch ? smawc : smaw)[sp];
            }
            tmp[jj] = vv;
          }
          acc = MFMA16(wC[ft][ck], packbf8(tmp), acc);
        }
#pragma unroll
        for (int r = 0; r < 4; ++r)
          locu[scol * 40 + ft * 16 + kq * 4 + r] = (ushort_t)f2bfbits(acc[r]);
      }
      // waits: ah(t) [AHF>=t+1]; WAR aw slot [PRF>=t-1]
      if (tid < 64) pollge(flg, AHF + tid, t + 1);
      else if (tid >= 64 && tid < 72) pollge(flg, PRF + tid - 64, t - 1);
      __syncthreads();
      // q = Wq . ah(t)
      {
        f32x4_t acc = {0,0,0,0};
        const ushort_t* hsrc = ahbU + (size_t)pc * 16384 + m16 * 1024;
#pragma unroll
        for (int c = 0; c < 32; ++c) {
          bf16x8_t bf = ldbf8_a(hsrc + c * 32 + kq * 8);
          acc = MFMA16(wq[c], bf, acc);
        }
        if (m16 == b) {
#pragma unroll
          for (int r = 0; r < 4; ++r) qsm[wid * 16 + kq * 4 + r] = acc[r];
        }
      }
      __syncthreads();
      // fused pa+e
#pragma unroll
      for (int u = 0; u < 2; ++u) {
        int sloc = (wid * 2 + u) * 16 + m16;
        bf16x8_t Bfrag = ldbf8(locu + sloc * 40 + kq * 8);
        float eacc = 0.f;
#pragma unroll
        for (int at = 0; at < 8; ++at) {
          f32x4_t C = {0,0,0,0};
          C = MFMA16(wLd[at], Bfrag, C);
#pragma unroll
          for (int r = 0; r < 4; ++r) {
            int a = at * 16 + kq * 4 + r;
            uint_t pw_ = pmreg[u][at][r >> 1];
            float pmv = bf2f((ushort_t)((r & 1) ? (pw_ >> 16) : (pw_ & 0xFFFF)));
            eacc = fmaf(vsm[a], ftanh(C[r] + qsm[a] + pmv), eacc);
          }
        }
        eacc += __shfl_xor(eacc, 16);
        eacc += __shfl_xor(eacc, 32);
        if (sloc >= mlenb) eacc = -1.0e9f;
        if (kq == 0) esm[sloc] = eacc;
      }
      __syncthreads();
      // softmax over 256
      float ev = 0.f;
      if (tid < 256) {
        ev = esm[tid];
        float mv = ev;
        for (int o = 32; o; o >>= 1) mv = fmaxf(mv, __shfl_xor(mv, o));
        if (lane == 0) red[wid] = mv;
      }
      __syncthreads();
      float gmax = fmaxf(fmaxf(red[0], red[1]), fmaxf(red[2], red[3]));
      float pv = 0.f;
      if (tid < 256) {
        pv = __expf(ev - gmax);
        float sv = pv;
        for (int o = 32; o; o >>= 1) sv += __shfl_xor(sv, o);
        if (lane == 0) red[8 + wid] = sv;
      }
      __syncthreads();
      float gsum = red[8] + red[9] + red[10] + red[11];
      if (tid < 256) {
        float awv = pv / gsum;
        smaw[tid] = awv;
        smawc[tid] += awv;
        out_al[((size_t)b * 400 + t) * 256 + tid] = awv;
        stf_a(awGF + (size_t)pc * 4096 + b * 256 + tid, awv);
      }
      __syncthreads();
      if (tid == 0) sig(flg, AWF + b, t + 1);
    }
  } else if (bid < 216) {
    // ======== PROJ path: mel/gate = Wdh.dh(t-1) + M.aw(t-1) + bias ========
    const int wv = (bid - 208) * 8 + wid;   // 0..63
    int rows[2] = {wv * 2, wv * 2 + 1};
    float wdh[2][16], mreg[2][16][4], biasr[2];
#pragma unroll
    for (int rr = 0; rr < 2; ++rr) {
      int row = rows[rr];
      biasr[rr] = 0.f;
#pragma unroll
      for (int j = 0; j < 16; ++j) wdh[rr][j] = 0.f;
#pragma unroll
      for (int b2 = 0; b2 < 16; ++b2)
#pragma unroll
        for (int j = 0; j < 4; ++j) mreg[rr][b2][j] = 0.f;
      if (row <= 80) {
        const float* wsrc = (row < 80) ? p.Wproj + (size_t)row * 1536 : p.Wgate;
#pragma unroll
        for (int j = 0; j < 16; ++j) wdh[rr][j] = wsrc[lane + 64 * j];
        biasr[rr] = (row < 80) ? p.bproj[row] : p.bgate[0];
#pragma unroll
        for (int b2 = 0; b2 < 16; ++b2)
#pragma unroll
          for (int j = 0; j < 4; ++j)
            mreg[rr][b2][j] = Mx[((size_t)b2 * 81 + row) * 256 + lane + 64 * j];
      }
    }
    float* awp = sm;  // 4096
    __syncthreads();
    for (int t = 1; t <= TSTEPS; ++t) {
      const int pw = (t + 1) & 1;
      if (tid < 128) pollge(flg, DHFL + tid, t);
      else if (tid < 144) pollge(flg, AWF + tid - 128, t);
      __syncthreads();
      for (int i = tid; i < 4096; i += 512)
        awp[i] = ldf_a(awGF + (size_t)pw * 4096 + i);
      __syncthreads();
      if (wv <= 40) {
        const size_t pp = (size_t)pw * 16384;
        for (int b2 = 0; b2 < 16; ++b2) {
          float h[16];
#pragma unroll
          for (int j = 0; j < 16; ++j) h[j] = ldf_a(dhfF + pp + b2 * 1024 + lane + 64 * j);
#pragma unroll
          for (int rr = 0; rr < 2; ++rr) {
            if (rows[rr] > 80) continue;
            float d = 0.f;
#pragma unroll
            for (int j = 0; j < 16; ++j) d = fmaf(wdh[rr][j], h[j], d);
#pragma unroll
            for (int j = 0; j < 4; ++j) d = fmaf(mreg[rr][b2][j], awp[b2 * 256 + lane + 64 * j], d);
            for (int o = 32; o; o >>= 1) d += __shfl_xor(d, o);
            if (lane == 0) {
              d += biasr[rr];
              if (rows[rr] < 80) out_mel[((size_t)b2 * 80 + rows[rr]) * 400 + (t - 1)] = d;
              else out_gate[(size_t)b2 * 400 + (t - 1)] = d;
            }
          }
        }
      }
      __syncthreads();
      if (tid == 0) sig(flg, PRF + (bid - 208), t);
    }
  }
  // bid >= 216: exit immediately
}

extern "C" void kernel_launch(void* const* d_in, const int* in_sizes, int n_in,
                              void* d_out, int out_size, void* d_ws, size_t ws_size,
                              hipStream_t stream) {
  (void)in_sizes; (void)n_in; (void)out_size; (void)ws_size;
  Ptrs p;
  p.memory = (const float*)d_in[0];
  p.dec_in = (const float*)d_in[1];
  p.Wpre1  = (const float*)d_in[2];
  p.Wpre2  = (const float*)d_in[3];
  p.Wih_a  = (const float*)d_in[4];
  p.Whh_a  = (const float*)d_in[5];
  p.bih_a  = (const float*)d_in[6];
  p.bhh_a  = (const float*)d_in[7];
  p.Wq     = (const float*)d_in[8];
  p.Wm     = (const float*)d_in[9];
  p.v      = (const float*)d_in[10];
  p.Wc     = (const float*)d_in[11];
  p.Wld    = (const float*)d_in[12];
  p.Wih_d  = (const float*)d_in[13];
  p.Whh_d  = (const float*)d_in[14];
  p.bih_d  = (const float*)d_in[15];
  p.bhh_d  = (const float*)d_in[16];
  p.Wproj  = (const float*)d_in[17];
  p.bproj  = (const float*)d_in[18];
  p.Wgate  = (const float*)d_in[19];
  p.bgate  = (const float*)d_in[20];
  p.mlen   = (const int*)d_in[21];
  p.ws  = (float*)d_ws;
  p.out = (float*)d_out;

  hipLaunchKernelGGL(k_zero,      dim3((ZERO_COUNT + 255) / 256), dim3(256), 0, stream, p);
  hipLaunchKernelGGL(k_transpose, dim3(336), dim3(256), 0, stream, p);
  hipLaunchKernelGGL(k_prenet,    dim3(400), dim3(256), 0, stream, p);
  hipLaunchKernelGGL(k_procmem,   dim3(256), dim3(256), 0, stream, p);
  hipLaunchKernelGGL(k_premix,    dim3(16),  dim3(512), 0, stream, p);
  hipLaunchKernelGGL(k_scan,      dim3(256), dim3(512), 0, stream, p);
}